// Round 9
// baseline (92.932 us; speedup 1.0000x reference)
//
#include <hip/hip_runtime.h>
#include <hip/hip_bf16.h>

#define N_TOT 8192
#define B_HALF 4096
#define D_DIM 256
#define NQUAD 496            // sum floor((64-ti)/4): 4-tile units
#define NSING 96             // sum (64-ti)%4: 1-tile tail units

typedef __attribute__((ext_vector_type(8))) short short8;
typedef __attribute__((ext_vector_type(4))) float f32x4;

// ZN_SCALE^2 = (1/TEMP)*log2(e) = 2*log2(e): acc = sim*log2(e), exp(sim)=exp2(acc)
#define ZN_SCALE 1.6986436f
#define LN2 0.69314718056f

__device__ inline unsigned short f2bf_rne(float x) {
  unsigned int u = __float_as_uint(x);
  u += 0x7fffu + ((u >> 16) & 1u);
  return (unsigned short)(u >> 16);
}
__device__ inline float bf2f(unsigned short u) {
  return __uint_as_float(((unsigned int)u) << 16);
}

// global->LDS direct (16B/lane). Dest must be wave-uniform; HW adds lane*16.
typedef __attribute__((address_space(3))) void lds_void;
typedef __attribute__((address_space(1))) const void glb_void;
__device__ __forceinline__ void gld16(const void* g, void* l) {
  __builtin_amdgcn_global_load_lds((glb_void*)g, (lds_void*)l, 16, 0, 0);
}

// ---- normalize + pos partials + rowsum/out zeroing -------------------------
__global__ __launch_bounds__(256) void k_norm(const float* __restrict__ p1,
                                              const float* __restrict__ p2,
                                              unsigned short* __restrict__ zn,
                                              float* __restrict__ self,
                                              float* __restrict__ partials,
                                              float* __restrict__ rowsum,
                                              float* __restrict__ out) {
  int tid = threadIdx.x;
  int lane = tid & 63;
  int w = tid >> 6;                 // wave 0..3
  int i = blockIdx.x * 4 + w;       // pair index 0..4095
  if (blockIdx.x < 32) rowsum[blockIdx.x * 256 + tid] = 0.0f; // zero for k_simlse
  if (blockIdx.x == 0 && tid == 0) out[0] = 0.0f;             // zero for k_lse
  float4 a = *reinterpret_cast<const float4*>(p1 + (size_t)i * D_DIM + lane * 4);
  float4 b = *reinterpret_cast<const float4*>(p2 + (size_t)i * D_DIM + lane * 4);
  float ssa = a.x * a.x + a.y * a.y + a.z * a.z + a.w * a.w;
  float ssb = b.x * b.x + b.y * b.y + b.z * b.z + b.w * b.w;
  float d = a.x * b.x + a.y * b.y + a.z * b.z + a.w * b.w;
#pragma unroll
  for (int m = 1; m < 64; m <<= 1) {
    ssa += __shfl_xor(ssa, m, 64);
    ssb += __shfl_xor(ssb, m, 64);
    d += __shfl_xor(d, m, 64);
  }
  float na = fmaxf(sqrtf(ssa), 1e-8f);
  float nb = fmaxf(sqrtf(ssb), 1e-8f);
  float ia = ZN_SCALE / na, ib = ZN_SCALE / nb;

  union { unsigned short us[4]; unsigned long long ll; } pa, pb;
  pa.us[0] = f2bf_rne(a.x * ia); pa.us[1] = f2bf_rne(a.y * ia);
  pa.us[2] = f2bf_rne(a.z * ia); pa.us[3] = f2bf_rne(a.w * ia);
  pb.us[0] = f2bf_rne(b.x * ib); pb.us[1] = f2bf_rne(b.y * ib);
  pb.us[2] = f2bf_rne(b.z * ib); pb.us[3] = f2bf_rne(b.w * ib);
  *reinterpret_cast<unsigned long long*>(zn + (size_t)i * D_DIM + lane * 4) = pa.ll;
  *reinterpret_cast<unsigned long long*>(zn + (size_t)(i + B_HALF) * D_DIM + lane * 4) = pb.ll;

  float sqa = 0.f, sqb = 0.f;
#pragma unroll
  for (int k = 0; k < 4; ++k) {
    float va = bf2f(pa.us[k]), vb = bf2f(pb.us[k]);
    sqa += va * va; sqb += vb * vb;
  }
#pragma unroll
  for (int m = 1; m < 64; m <<= 1) {
    sqa += __shfl_xor(sqa, m, 64);
    sqb += __shfl_xor(sqb, m, 64);
  }
  __shared__ float red[4];
  if (lane == 0) {
    self[i] = sqa;
    self[i + B_HALF] = sqb;
    red[w] = -4.0f * d / (na * nb) * (1.0f / (float)N_TOT);
  }
  __syncthreads();
  if (tid == 0) partials[blockIdx.x] = red[0] + red[1] + red[2] + red[3];
}

// ---- symmetric fused GEMM + exp row/col sums; one kernel per unit size -----
// NT=4: quad units (496 blocks, all co-resident). NT=1: single-tile tail (96).
// Per unit: row-band ti (128 rows, A frags in regs), col-tiles tj0..tj0+NT-1.
// Row-sums -> ti rows; col-sums -> tj rows (skipped on diagonal tile).
// R5 machinery: wave-private LDS dbufs, global_load_lds, counted vmcnt,
// zero main-loop barriers, all trip counts compile-time.
template <int NT>
__global__ __launch_bounds__(256, 2) void k_simlse(const unsigned short* __restrict__ zn,
                                                   float* __restrict__ rowsum) {
  __shared__ __align__(16) char S[65536]; // A bounce (64KB), then 4 x 16KB wave dbufs

  constexpr int NHT = 2 * NT; // 64-col steps
  constexpr int NPH = 4 * NT; // staging phases (K halves)

  // decode bid -> (ti, tj0)
  const int bid = blockIdx.x;
  int ti = 0, cum = 0, tj0;
  if constexpr (NT == 4) {
    while (cum + ((64 - ti) >> 2) <= bid) { cum += (64 - ti) >> 2; ++ti; }
    tj0 = ti + 4 * (bid - cum);
  } else {
    while (cum + ((64 - ti) & 3) <= bid) { cum += (64 - ti) & 3; ++ti; }
    tj0 = 64 - ((64 - ti) & 3) + (bid - cum);
  }
  const bool diag = (tj0 == ti);
  const int rowbase = ti * 128;
  const int colchunk = tj0 * 128;

  const int tid = threadIdx.x;
  const int lane = tid & 63;
  const int wid = tid >> 6;
  const int wm = wid >> 1;  // row half
  const int wn = wid & 1;   // col half
  const int hi = lane >> 4; // 0..3
  const int lo = lane & 15;
  const int sw = lane & 7;
  const char* zb = (const char*)zn;

  // ---- stage A: 128 rows x 256 K, swizzled via pre-swizzled global source --
#pragma unroll
  for (int i = 0; i < 16; ++i) {
    int qq = i * 256 + tid;
    int row = qq >> 5, c8s = qq & 31;
    gld16(zb + (((size_t)(rowbase + row)) << 9) + ((size_t)(c8s ^ (row & 7)) << 4),
          S + i * 4096 + wid * 1024);
  }
  __syncthreads(); // drains vmcnt(0) + barrier

  // ---- A fragments -> registers (block-invariant) ----
  short8 af[4][8]; // [m][k8], 128 VGPRs
#pragma unroll
  for (int m = 0; m < 4; ++m) {
    int row = wm * 64 + m * 16 + lo;
#pragma unroll
    for (int k8 = 0; k8 < 8; ++k8) {
      int c8 = k8 * 4 + hi;
      af[m][k8] = *reinterpret_cast<const short8*>(S + row * 512 + ((c8 ^ (row & 7)) << 4));
    }
  }
  __syncthreads(); // all waves done reading A; B buffers may overlay

  char* Bw = S + wid * 16384; // wave-private 2 x 8KB dbuf

  // stage phase p: t=p>>1 (64-col step), kh=p&1 (K half). 32 cols x 128 K.
  auto stage = [&](int p) {
    char* dst = Bw + (p & 1) * 8192;
    const int c0 = colchunk + (p >> 1) * 64 + wn * 32;
    const size_t khoff = (size_t)(p & 1) << 8; // kh*128K*2B
#pragma unroll
    for (int i = 0; i < 8; ++i) {
      const int crow = 4 * i + hi;
      const int c8l = lo ^ (((i & 1) << 2) | hi);
      gld16(zb + (((size_t)(c0 + crow)) << 9) + khoff + ((size_t)c8l << 4),
            dst + i * 1024);
    }
  };

  // prologue: 2 phases in flight (NPH >= 4 when NT=1: NPH=4; ok)
  stage(0);
  stage(1);

  float pr[4][4] = {}; // [m][r] per-row exp partials (rows of ti)

#pragma unroll
  for (int t = 0; t < NHT; ++t) {
    f32x4 acc[4][2];
#pragma unroll
    for (int m = 0; m < 4; ++m)
#pragma unroll
      for (int n = 0; n < 2; ++n) acc[m][n] = (f32x4){0.f, 0.f, 0.f, 0.f};

#pragma unroll
    for (int kh = 0; kh < 2; ++kh) {
      const int p = t * 2 + kh;
      char* Bc = Bw + (p & 1) * 8192;

      // own-wave counted wait: phase p's 8 loads done; later phases fly on
      if (p == NPH - 1) {
        asm volatile("s_waitcnt vmcnt(0)" ::: "memory");
      } else {
        asm volatile("s_waitcnt vmcnt(8)" ::: "memory");
      }
      __builtin_amdgcn_sched_barrier(0);

      short8 bf[2][4];
#pragma unroll
      for (int n = 0; n < 2; ++n) {
        const int crow = n * 16 + lo;
        const char* rb = Bc + crow * 256;
#pragma unroll
        for (int ks = 0; ks < 4; ++ks)
          bf[n][ks] = *reinterpret_cast<const short8*>(rb + (((ks * 4 + hi) ^ sw) << 4));
      }
      asm volatile("s_waitcnt lgkmcnt(0)" ::: "memory");
      __builtin_amdgcn_sched_barrier(0);
      // refill the buffer we just read (lands under the MFMAs)
      if (p + 2 < NPH) stage(p + 2);

      __builtin_amdgcn_s_setprio(1);
#pragma unroll
      for (int ks = 0; ks < 4; ++ks)
#pragma unroll
        for (int m = 0; m < 4; ++m) {
          acc[m][0] = __builtin_amdgcn_mfma_f32_16x16x32_bf16(af[m][kh * 4 + ks], bf[0][ks], acc[m][0], 0, 0, 0);
          acc[m][1] = __builtin_amdgcn_mfma_f32_16x16x32_bf16(af[m][kh * 4 + ks], bf[1][ks], acc[m][1], 0, 0, 0);
        }
      __builtin_amdgcn_s_setprio(0);
      __builtin_amdgcn_sched_barrier(0);
    }

    // retire 64-col step: exp2, accumulate row partials + this step's col partials
    float pc[2] = {0.f, 0.f};
#pragma unroll
    for (int m = 0; m < 4; ++m)
#pragma unroll
      for (int n = 0; n < 2; ++n) {
        float e0 = __builtin_amdgcn_exp2f(acc[m][n][0]);
        float e1 = __builtin_amdgcn_exp2f(acc[m][n][1]);
        float e2 = __builtin_amdgcn_exp2f(acc[m][n][2]);
        float e3 = __builtin_amdgcn_exp2f(acc[m][n][3]);
        pr[m][0] += e0; pr[m][1] += e1; pr[m][2] += e2; pr[m][3] += e3;
        pc[n] += (e0 + e1) + (e2 + e3);
      }

    // col sums -> rows of tj (skip the diagonal tile: first 2 steps when diag)
    if (!(diag && t < 2)) {
#pragma unroll
      for (int n = 0; n < 2; ++n) {
        float v = pc[n];
        v += __shfl_xor(v, 16, 64);
        v += __shfl_xor(v, 32, 64);
        if (hi == 0)
          atomicAdd(&rowsum[colchunk + t * 64 + wn * 32 + n * 16 + lo], v);
      }
    }
  }

  // row sums -> rows of ti (reduce over the 16 col-lanes)
#pragma unroll
  for (int m = 0; m < 4; ++m)
#pragma unroll
    for (int r = 0; r < 4; ++r) {
      float s = pr[m][r];
      s += __shfl_xor(s, 1, 64);
      s += __shfl_xor(s, 2, 64);
      s += __shfl_xor(s, 4, 64);
      s += __shfl_xor(s, 8, 64);
      if (lo == 0)
        atomicAdd(&rowsum[rowbase + wm * 64 + m * 16 + hi * 4 + r], s);
    }
}

// ---- final: 32 blocks, out += sum(log(rowsum-exp2(self)))/n + partials -----
__global__ __launch_bounds__(256) void k_lse(const float* __restrict__ rowsum,
                                             const float* __restrict__ self,
                                             const float* __restrict__ partials,
                                             float* __restrict__ out) {
  int tid = threadIdx.x;
  int i = blockIdx.x * 256 + tid;
  float rs = rowsum[i] - __builtin_amdgcn_exp2f(self[i]);
  float v = __builtin_amdgcn_logf(rs) * (LN2 / (float)N_TOT); // v_log_f32 = log2
  if (tid < 32) v += partials[blockIdx.x * 32 + tid]; // 1024 partials / 32 blocks
#pragma unroll
  for (int m = 1; m < 64; m <<= 1) v += __shfl_xor(v, m, 64);
  __shared__ float red[4];
  if ((tid & 63) == 0) red[tid >> 6] = v;
  __syncthreads();
  if (tid == 0) atomicAdd(out, red[0] + red[1] + red[2] + red[3]);
}

extern "C" void kernel_launch(void* const* d_in, const int* in_sizes, int n_in,
                              void* d_out, int out_size, void* d_ws, size_t ws_size,
                              hipStream_t stream) {
  const float* p1 = (const float*)d_in[0];
  const float* p2 = (const float*)d_in[1];
  float* out = (float*)d_out;
  char* ws = (char*)d_ws;

  unsigned short* zn = (unsigned short*)ws;                      // 4 MB
  float* self = (float*)(ws + (size_t)N_TOT * D_DIM * 2);        // 32 KB
  float* rowsum = self + N_TOT;                                  // 32 KB
  float* partials = rowsum + N_TOT;                              // 4 KB

  k_norm<<<B_HALF / 4, 256, 0, stream>>>(p1, p2, zn, self, partials, rowsum, out);
  k_simlse<4><<<NQUAD, 256, 0, stream>>>(zn, rowsum);
  k_simlse<1><<<NSING, 256, 0, stream>>>(zn, rowsum);
  k_lse<<<N_TOT / 256, 256, 0, stream>>>(rowsum, self, partials, out);
}

// Round 10
// 46.450 us; speedup vs baseline: 2.0007x; 2.0007x over previous
//
#include <hip/hip_runtime.h>
#include <hip/hip_bf16.h>

#define N_TOT 8192
#define B_HALF 4096
#define D_DIM 256
#define NQUAD 496            // sum floor((64-ti)/4): 4-tile units
#define NSING 96             // sum (64-ti)%4: 1-tile tail units

typedef __attribute__((ext_vector_type(8))) short short8;
typedef __attribute__((ext_vector_type(4))) float f32x4;

// ZN_SCALE^2 = (1/TEMP)*log2(e) = 2*log2(e): acc = sim*log2(e), exp(sim)=exp2(acc)
#define ZN_SCALE 1.6986436f
#define LN2 0.69314718056f

__device__ inline unsigned short f2bf_rne(float x) {
  unsigned int u = __float_as_uint(x);
  u += 0x7fffu + ((u >> 16) & 1u);
  return (unsigned short)(u >> 16);
}
__device__ inline float bf2f(unsigned short u) {
  return __uint_as_float(((unsigned int)u) << 16);
}

// global->LDS direct (16B/lane). Dest must be wave-uniform; HW adds lane*16.
typedef __attribute__((address_space(3))) void lds_void;
typedef __attribute__((address_space(1))) const void glb_void;
__device__ __forceinline__ void gld16(const void* g, void* l) {
  __builtin_amdgcn_global_load_lds((glb_void*)g, (lds_void*)l, 16, 0, 0);
}

// ---- normalize + pos partials + rowsum/out zeroing -------------------------
__global__ __launch_bounds__(256) void k_norm(const float* __restrict__ p1,
                                              const float* __restrict__ p2,
                                              unsigned short* __restrict__ zn,
                                              float* __restrict__ self,
                                              float* __restrict__ partials,
                                              float* __restrict__ rowsum,
                                              float* __restrict__ out) {
  int tid = threadIdx.x;
  int lane = tid & 63;
  int w = tid >> 6;                 // wave 0..3
  int i = blockIdx.x * 4 + w;       // pair index 0..4095
  if (blockIdx.x < 32) rowsum[blockIdx.x * 256 + tid] = 0.0f; // zero for k_simlse
  if (blockIdx.x == 0 && tid == 0) out[0] = 0.0f;             // zero for k_lse
  float4 a = *reinterpret_cast<const float4*>(p1 + (size_t)i * D_DIM + lane * 4);
  float4 b = *reinterpret_cast<const float4*>(p2 + (size_t)i * D_DIM + lane * 4);
  float ssa = a.x * a.x + a.y * a.y + a.z * a.z + a.w * a.w;
  float ssb = b.x * b.x + b.y * b.y + b.z * b.z + b.w * b.w;
  float d = a.x * b.x + a.y * b.y + a.z * b.z + a.w * b.w;
#pragma unroll
  for (int m = 1; m < 64; m <<= 1) {
    ssa += __shfl_xor(ssa, m, 64);
    ssb += __shfl_xor(ssb, m, 64);
    d += __shfl_xor(d, m, 64);
  }
  float na = fmaxf(sqrtf(ssa), 1e-8f);
  float nb = fmaxf(sqrtf(ssb), 1e-8f);
  float ia = ZN_SCALE / na, ib = ZN_SCALE / nb;

  union { unsigned short us[4]; unsigned long long ll; } pa, pb;
  pa.us[0] = f2bf_rne(a.x * ia); pa.us[1] = f2bf_rne(a.y * ia);
  pa.us[2] = f2bf_rne(a.z * ia); pa.us[3] = f2bf_rne(a.w * ia);
  pb.us[0] = f2bf_rne(b.x * ib); pb.us[1] = f2bf_rne(b.y * ib);
  pb.us[2] = f2bf_rne(b.z * ib); pb.us[3] = f2bf_rne(b.w * ib);
  *reinterpret_cast<unsigned long long*>(zn + (size_t)i * D_DIM + lane * 4) = pa.ll;
  *reinterpret_cast<unsigned long long*>(zn + (size_t)(i + B_HALF) * D_DIM + lane * 4) = pb.ll;

  float sqa = 0.f, sqb = 0.f;
#pragma unroll
  for (int k = 0; k < 4; ++k) {
    float va = bf2f(pa.us[k]), vb = bf2f(pb.us[k]);
    sqa += va * va; sqb += vb * vb;
  }
#pragma unroll
  for (int m = 1; m < 64; m <<= 1) {
    sqa += __shfl_xor(sqa, m, 64);
    sqb += __shfl_xor(sqb, m, 64);
  }
  __shared__ float red[4];
  if (lane == 0) {
    self[i] = sqa;
    self[i + B_HALF] = sqb;
    red[w] = -4.0f * d / (na * nb) * (1.0f / (float)N_TOT);
  }
  __syncthreads();
  if (tid == 0) partials[blockIdx.x] = red[0] + red[1] + red[2] + red[3];
}

// ---- symmetric fused GEMM + exp row/col sums; one kernel per unit size -----
// A/B probe vs R9: __launch_bounds__(256,1) lifts the 128-VGPR allocator cap
// (R8/R9 spilled af[4][8] to scratch: 80MB FETCH + 86MB WRITE); outer t-loop
// pinned to unroll 1 to cap transient register pressure. Everything else
// identical to R9 (wave-private LDS dbufs, global_load_lds, counted vmcnt,
// zero main-loop barriers).
template <int NT>
__global__ __launch_bounds__(256, 1) void k_simlse(const unsigned short* __restrict__ zn,
                                                   float* __restrict__ rowsum) {
  __shared__ __align__(16) char S[65536]; // A bounce (64KB), then 4 x 16KB wave dbufs

  constexpr int NHT = 2 * NT; // 64-col steps
  constexpr int NPH = 4 * NT; // staging phases (K halves)

  // decode bid -> (ti, tj0)
  const int bid = blockIdx.x;
  int ti = 0, cum = 0, tj0;
  if constexpr (NT == 4) {
    while (cum + ((64 - ti) >> 2) <= bid) { cum += (64 - ti) >> 2; ++ti; }
    tj0 = ti + 4 * (bid - cum);
  } else {
    while (cum + ((64 - ti) & 3) <= bid) { cum += (64 - ti) & 3; ++ti; }
    tj0 = 64 - ((64 - ti) & 3) + (bid - cum);
  }
  const bool diag = (tj0 == ti);
  const int rowbase = ti * 128;
  const int colchunk = tj0 * 128;

  const int tid = threadIdx.x;
  const int lane = tid & 63;
  const int wid = tid >> 6;
  const int wm = wid >> 1;  // row half
  const int wn = wid & 1;   // col half
  const int hi = lane >> 4; // 0..3
  const int lo = lane & 15;
  const int sw = lane & 7;
  const char* zb = (const char*)zn;

  // ---- stage A: 128 rows x 256 K, swizzled via pre-swizzled global source --
#pragma unroll
  for (int i = 0; i < 16; ++i) {
    int qq = i * 256 + tid;
    int row = qq >> 5, c8s = qq & 31;
    gld16(zb + (((size_t)(rowbase + row)) << 9) + ((size_t)(c8s ^ (row & 7)) << 4),
          S + i * 4096 + wid * 1024);
  }
  __syncthreads(); // drains vmcnt(0) + barrier

  // ---- A fragments -> registers (block-invariant) ----
  short8 af[4][8]; // [m][k8], 128 VGPRs
#pragma unroll
  for (int m = 0; m < 4; ++m) {
    int row = wm * 64 + m * 16 + lo;
#pragma unroll
    for (int k8 = 0; k8 < 8; ++k8) {
      int c8 = k8 * 4 + hi;
      af[m][k8] = *reinterpret_cast<const short8*>(S + row * 512 + ((c8 ^ (row & 7)) << 4));
    }
  }
  __syncthreads(); // all waves done reading A; B buffers may overlay

  char* Bw = S + wid * 16384; // wave-private 2 x 8KB dbuf

  // stage phase p: t=p>>1 (64-col step), kh=p&1 (K half). 32 cols x 128 K.
  auto stage = [&](int p) {
    char* dst = Bw + (p & 1) * 8192;
    const int c0 = colchunk + (p >> 1) * 64 + wn * 32;
    const size_t khoff = (size_t)(p & 1) << 8; // kh*128K*2B
#pragma unroll
    for (int i = 0; i < 8; ++i) {
      const int crow = 4 * i + hi;
      const int c8l = lo ^ (((i & 1) << 2) | hi);
      gld16(zb + (((size_t)(c0 + crow)) << 9) + khoff + ((size_t)c8l << 4),
            dst + i * 1024);
    }
  };

  // prologue: 2 phases in flight (NPH >= 4 always)
  stage(0);
  stage(1);

  float pr[4][4] = {}; // [m][r] per-row exp partials (rows of ti)

#pragma unroll 1
  for (int t = 0; t < NHT; ++t) {
    f32x4 acc[4][2];
#pragma unroll
    for (int m = 0; m < 4; ++m)
#pragma unroll
      for (int n = 0; n < 2; ++n) acc[m][n] = (f32x4){0.f, 0.f, 0.f, 0.f};

#pragma unroll
    for (int kh = 0; kh < 2; ++kh) {
      const int p = t * 2 + kh;
      char* Bc = Bw + (p & 1) * 8192;

      // own-wave counted wait: phase p's 8 loads done; later phases fly on
      if (p == NPH - 1) {
        asm volatile("s_waitcnt vmcnt(0)" ::: "memory");
      } else {
        asm volatile("s_waitcnt vmcnt(8)" ::: "memory");
      }
      __builtin_amdgcn_sched_barrier(0);

      short8 bf[2][4];
#pragma unroll
      for (int n = 0; n < 2; ++n) {
        const int crow = n * 16 + lo;
        const char* rb = Bc + crow * 256;
#pragma unroll
        for (int ks = 0; ks < 4; ++ks)
          bf[n][ks] = *reinterpret_cast<const short8*>(rb + (((ks * 4 + hi) ^ sw) << 4));
      }
      asm volatile("s_waitcnt lgkmcnt(0)" ::: "memory");
      __builtin_amdgcn_sched_barrier(0);
      // refill the buffer we just read (lands under the MFMAs)
      if (p + 2 < NPH) stage(p + 2);

      __builtin_amdgcn_s_setprio(1);
#pragma unroll
      for (int ks = 0; ks < 4; ++ks)
#pragma unroll
        for (int m = 0; m < 4; ++m) {
          acc[m][0] = __builtin_amdgcn_mfma_f32_16x16x32_bf16(af[m][kh * 4 + ks], bf[0][ks], acc[m][0], 0, 0, 0);
          acc[m][1] = __builtin_amdgcn_mfma_f32_16x16x32_bf16(af[m][kh * 4 + ks], bf[1][ks], acc[m][1], 0, 0, 0);
        }
      __builtin_amdgcn_s_setprio(0);
      __builtin_amdgcn_sched_barrier(0);
    }

    // retire 64-col step: exp2, accumulate row partials + this step's col partials
    float pc[2] = {0.f, 0.f};
#pragma unroll
    for (int m = 0; m < 4; ++m)
#pragma unroll
      for (int n = 0; n < 2; ++n) {
        float e0 = __builtin_amdgcn_exp2f(acc[m][n][0]);
        float e1 = __builtin_amdgcn_exp2f(acc[m][n][1]);
        float e2 = __builtin_amdgcn_exp2f(acc[m][n][2]);
        float e3 = __builtin_amdgcn_exp2f(acc[m][n][3]);
        pr[m][0] += e0; pr[m][1] += e1; pr[m][2] += e2; pr[m][3] += e3;
        pc[n] += (e0 + e1) + (e2 + e3);
      }

    // col sums -> rows of tj (skip the diagonal tile: first 2 steps when diag)
    if (!(diag && t < 2)) {
#pragma unroll
      for (int n = 0; n < 2; ++n) {
        float v = pc[n];
        v += __shfl_xor(v, 16, 64);
        v += __shfl_xor(v, 32, 64);
        if (hi == 0)
          atomicAdd(&rowsum[colchunk + t * 64 + wn * 32 + n * 16 + lo], v);
      }
    }
  }

  // row sums -> rows of ti (reduce over the 16 col-lanes)
#pragma unroll
  for (int m = 0; m < 4; ++m)
#pragma unroll
    for (int r = 0; r < 4; ++r) {
      float s = pr[m][r];
      s += __shfl_xor(s, 1, 64);
      s += __shfl_xor(s, 2, 64);
      s += __shfl_xor(s, 4, 64);
      s += __shfl_xor(s, 8, 64);
      if (lo == 0)
        atomicAdd(&rowsum[rowbase + wm * 64 + m * 16 + hi * 4 + r], s);
    }
}

// ---- final: 32 blocks, out += sum(log(rowsum-exp2(self)))/n + partials -----
__global__ __launch_bounds__(256) void k_lse(const float* __restrict__ rowsum,
                                             const float* __restrict__ self,
                                             const float* __restrict__ partials,
                                             float* __restrict__ out) {
  int tid = threadIdx.x;
  int i = blockIdx.x * 256 + tid;
  float rs = rowsum[i] - __builtin_amdgcn_exp2f(self[i]);
  float v = __builtin_amdgcn_logf(rs) * (LN2 / (float)N_TOT); // v_log_f32 = log2
  if (tid < 32) v += partials[blockIdx.x * 32 + tid]; // 1024 partials / 32 blocks
#pragma unroll
  for (int m = 1; m < 64; m <<= 1) v += __shfl_xor(v, m, 64);
  __shared__ float red[4];
  if ((tid & 63) == 0) red[tid >> 6] = v;
  __syncthreads();
  if (tid == 0) atomicAdd(out, red[0] + red[1] + red[2] + red[3]);
}

extern "C" void kernel_launch(void* const* d_in, const int* in_sizes, int n_in,
                              void* d_out, int out_size, void* d_ws, size_t ws_size,
                              hipStream_t stream) {
  const float* p1 = (const float*)d_in[0];
  const float* p2 = (const float*)d_in[1];
  float* out = (float*)d_out;
  char* ws = (char*)d_ws;

  unsigned short* zn = (unsigned short*)ws;                      // 4 MB
  float* self = (float*)(ws + (size_t)N_TOT * D_DIM * 2);        // 32 KB
  float* rowsum = self + N_TOT;                                  // 32 KB
  float* partials = rowsum + N_TOT;                              // 4 KB

  k_norm<<<B_HALF / 4, 256, 0, stream>>>(p1, p2, zn, self, partials, rowsum, out);
  k_simlse<4><<<NQUAD, 256, 0, stream>>>(zn, rowsum);
  k_simlse<1><<<NSING, 256, 0, stream>>>(zn, rowsum);
  k_lse<<<N_TOT / 256, 256, 0, stream>>>(rowsum, self, partials, out);
}